// Round 14
// baseline (53.973 us; speedup 1.0000x reference)
//
#include <hip/hip_runtime.h>

namespace {

constexpr int NB = 4, ND = 128, NH = 192, NW = 192;
constexpr int PLI = NH * NW;
constexpr int CD = 16;    // output planes per block; 128/16 = 8 exact

__global__ __launch_bounds__(256, 2)
void edge_loss3d(const float* __restrict__ pred,
                 const float* __restrict__ targ,
                 float* __restrict__ out)
{
    const int lane = threadIdx.x & 63;
    const int wid  = threadIdx.x >> 6;
    const int d0   = blockIdx.x * CD;
    const int h    = blockIdx.y * 4 + wid;    // this wave's output row, 0..191
    const int b    = blockIdx.z;

    // per-lane bases: 3 w-elements per lane, all 64 lanes active
    const float* sb0 = pred + (size_t)b * ND * PLI + 3 * lane;
    const float* sb1 = targ + (size_t)b * ND * PLI + 3 * lane;

    // clamped row offsets + wave-uniform h-boundary masks
    const int ro0 = (h - 1 < 0 ? 0 : h - 1) * NW;
    const int ro1 = h * NW;
    const int ro2 = (h + 1 > NH - 1 ? NH - 1 : h + 1) * NW;
    const float m0 = (h - 1 >= 0) ? 1.f : 0.f;
    const float m2 = (h + 1 < NH) ? 1.f : 0.f;

    // rolling UNSCALED conv state: q[tensor][slot][kind 0=ss 1=ts 2=st][w]
    float q[2][3][3][3];
    float acc = 0.f;

// one tensor, one plane (in-range), into slot SP. h-conv in registers,
// w-halo of (u,v) via in-wave shuffles.
#define TPASS(T, SP, OFS) do {                                                \
    const float* s_ = (T) ? sb1 : sb0;                                        \
    float a0_ = s_[(OFS) + ro0], a1_ = s_[(OFS) + ro0 + 1], a2_ = s_[(OFS) + ro0 + 2]; \
    float b0_ = s_[(OFS) + ro1], b1_ = s_[(OFS) + ro1 + 1], b2_ = s_[(OFS) + ro1 + 2]; \
    float c0_ = s_[(OFS) + ro2], c1_ = s_[(OFS) + ro2 + 1], c2_ = s_[(OFS) + ro2 + 2]; \
    a0_ *= m0; a1_ *= m0; a2_ *= m0;                                          \
    c0_ *= m2; c1_ *= m2; c2_ *= m2;                                          \
    float u0_ = fmaf(2.f, b0_, a0_ + c0_);                                    \
    float u1_ = fmaf(2.f, b1_, a1_ + c1_);                                    \
    float u2_ = fmaf(2.f, b2_, a2_ + c2_);                                    \
    float v0_ = c0_ - a0_, v1_ = c1_ - a1_, v2_ = c2_ - a2_;                  \
    MASKUV                                                                    \
    float um_ = __shfl_up(u2_, 1, 64);                                        \
    float vm_ = __shfl_up(v2_, 1, 64);                                        \
    float up_ = __shfl_down(u0_, 1, 64);                                      \
    float vp_ = __shfl_down(v0_, 1, 64);                                      \
    if (lane == 0)  { um_ = 0.f; vm_ = 0.f; }                                 \
    if (lane == 63) { up_ = 0.f; vp_ = 0.f; }                                 \
    q[T][SP][0][0] = fmaf(2.f, u0_, um_ + u1_);                               \
    q[T][SP][0][1] = fmaf(2.f, u1_, u0_ + u2_);                               \
    q[T][SP][0][2] = fmaf(2.f, u2_, u1_ + up_);                               \
    q[T][SP][1][0] = fmaf(2.f, v0_, vm_ + v1_);                               \
    q[T][SP][1][1] = fmaf(2.f, v1_, v0_ + v2_);                               \
    q[T][SP][1][2] = fmaf(2.f, v2_, v1_ + vp_);                               \
    q[T][SP][2][0] = u1_ - um_;                                               \
    q[T][SP][2][1] = u2_ - u0_;                                               \
    q[T][SP][2][2] = up_ - u1_;                                               \
} while (0)

// both tensors, plane P guaranteed in range
#define TPP(SP, P) do {                                                       \
    const int o_ = (P) * PLI;                                                 \
    TPASS(0, SP, o_); TPASS(1, SP, o_);                                       \
} while (0)

// both tensors, plane P may be out of range (block at d-edge): clamp + mask
#define TPM(SP, P) do {                                                       \
    const int pc_ = (P) < 0 ? 0 : ((P) > ND - 1 ? ND - 1 : (P));              \
    const float pm_ = ((P) >= 0 && (P) < ND) ? 1.f : 0.f;                     \
    const int o_ = pc_ * PLI;                                                 \
    TPASS_M(0, SP, o_, pm_); TPASS_M(1, SP, o_, pm_);                         \
} while (0)

#define MASKUV
#define TPASS_BODY TPASS
// masked variant: zero u,v by plane mask (linear -> zeroes ss/ts/st too)
#define TPASS_M(T, SP, OFS, PM)                                               \
    do {                                                                      \
        const float* s_ = (T) ? sb1 : sb0;                                    \
        float a0_ = s_[(OFS) + ro0], a1_ = s_[(OFS) + ro0 + 1], a2_ = s_[(OFS) + ro0 + 2]; \
        float b0_ = s_[(OFS) + ro1], b1_ = s_[(OFS) + ro1 + 1], b2_ = s_[(OFS) + ro1 + 2]; \
        float c0_ = s_[(OFS) + ro2], c1_ = s_[(OFS) + ro2 + 1], c2_ = s_[(OFS) + ro2 + 2]; \
        a0_ *= m0; a1_ *= m0; a2_ *= m0;                                      \
        c0_ *= m2; c1_ *= m2; c2_ *= m2;                                      \
        float u0_ = fmaf(2.f, b0_, a0_ + c0_) * (PM);                         \
        float u1_ = fmaf(2.f, b1_, a1_ + c1_) * (PM);                         \
        float u2_ = fmaf(2.f, b2_, a2_ + c2_) * (PM);                         \
        float v0_ = (c0_ - a0_) * (PM), v1_ = (c1_ - a1_) * (PM), v2_ = (c2_ - a2_) * (PM); \
        float um_ = __shfl_up(u2_, 1, 64);                                    \
        float vm_ = __shfl_up(v2_, 1, 64);                                    \
        float up_ = __shfl_down(u0_, 1, 64);                                  \
        float vp_ = __shfl_down(v0_, 1, 64);                                  \
        if (lane == 0)  { um_ = 0.f; vm_ = 0.f; }                             \
        if (lane == 63) { up_ = 0.f; vp_ = 0.f; }                             \
        q[T][SP][0][0] = fmaf(2.f, u0_, um_ + u1_);                           \
        q[T][SP][0][1] = fmaf(2.f, u1_, u0_ + u2_);                           \
        q[T][SP][0][2] = fmaf(2.f, u2_, u1_ + up_);                           \
        q[T][SP][1][0] = fmaf(2.f, v0_, vm_ + v1_);                           \
        q[T][SP][1][1] = fmaf(2.f, v1_, v0_ + v2_);                           \
        q[T][SP][1][2] = fmaf(2.f, v2_, v1_ + vp_);                           \
        q[T][SP][2][0] = u1_ - um_;                                           \
        q[T][SP][2][1] = u2_ - u0_;                                           \
        q[T][SP][2][2] = up_ - u1_;                                           \
    } while (0)

// unscaled magnitude: conv scales are exactly 16x; eps_u = 256e-8; v_sqrt 1 inst
#define EDGE1(T, J, SM, SC, SP, E) do {                                       \
    const float gx_ = fmaf(2.f, q[T][SC][2][J], q[T][SM][2][J] + q[T][SP][2][J]); \
    const float gy_ = fmaf(2.f, q[T][SC][1][J], q[T][SM][1][J] + q[T][SP][1][J]); \
    const float gz_ = q[T][SP][0][J] - q[T][SM][0][J];                        \
    const float d_ = fmaf(gz_, gz_, fmaf(gy_, gy_, fmaf(gx_, gx_, 2.56e-6f)));\
    asm("v_sqrt_f32 %0, %1" : "=v"(E) : "v"(d_));                             \
} while (0)

#define EMIT(SM, SC, SP) do {                                                 \
    float e0_, e1_;                                                           \
    EDGE1(0, 0, SM, SC, SP, e0_); EDGE1(1, 0, SM, SC, SP, e1_); acc += fabsf(e0_ - e1_); \
    EDGE1(0, 1, SM, SC, SP, e0_); EDGE1(1, 1, SM, SC, SP, e1_); acc += fabsf(e0_ - e1_); \
    EDGE1(0, 2, SM, SC, SP, e0_); EDGE1(1, 2, SM, SC, SP, e1_); acc += fabsf(e0_ - e1_); \
} while (0)

    // 18 phases k=0..17: plane d0-1+k -> slot k%3; EMIT from k>=2. No barriers.
    TPM(0, d0 - 1);                           // k=0 (OOB only for first block)
    TPP(1, d0);                               // k=1
    for (int gg = 0; gg < 5; ++gg) {          // k=2..16
        const int p = d0 + 1 + 3 * gg;
        TPP(2, p);     EMIT(0, 1, 2);
        TPP(0, p + 1); EMIT(1, 2, 0);
        TPP(1, p + 2); EMIT(2, 0, 1);
    }
    TPM(2, d0 + 16); EMIT(0, 1, 2);           // k=17 (OOB only for last block)

#undef TPASS
#undef TPASS_M
#undef TPP
#undef TPM
#undef MASKUV
#undef TPASS_BODY
#undef EDGE1
#undef EMIT

    // wave reduce -> block reduce -> one atomic per block
    #pragma unroll
    for (int off = 32; off > 0; off >>= 1)
        acc += __shfl_down(acc, off, 64);
    __shared__ float wsum[4];
    if (lane == 0) wsum[wid] = acc;
    __syncthreads();
    if (threadIdx.x == 0) {
        // fold the exact 1/16 kernel scale and the mean into one constant
        const float invN = 1.f / (16.f * (float)((long long)NB * ND * NH * NW));
        atomicAdd(out, (wsum[0] + wsum[1] + wsum[2] + wsum[3]) * invN);
    }
}

} // namespace

extern "C" void kernel_launch(void* const* d_in, const int* in_sizes, int n_in,
                              void* d_out, int out_size, void* d_ws, size_t ws_size,
                              hipStream_t stream) {
    const float* pred = (const float*)d_in[0];
    const float* targ = (const float*)d_in[1];
    float* out = (float*)d_out;
    (void)in_sizes; (void)n_in; (void)out_size; (void)d_ws; (void)ws_size;

    hipMemsetAsync(out, 0, sizeof(float), stream);

    dim3 grid(ND / CD, NH / 4, NB);   // (8, 48, 4) = 1536 blocks
    dim3 block(256);
    edge_loss3d<<<grid, block, 0, stream>>>(pred, targ, out);
}

// Round 15
// 44.788 us; speedup vs baseline: 1.2051x; 1.2051x over previous
//
#include <hip/hip_runtime.h>

namespace {

constexpr int NB = 4, ND = 128, NH = 192, NW = 192;
constexpr int PLI = NH * NW;
constexpr int CD = 16;    // output planes per block; 128/16 = 8 exact

__global__ __launch_bounds__(256, 2)
void edge_loss3d(const float* __restrict__ pred,
                 const float* __restrict__ targ,
                 float* __restrict__ out)
{
    const int lane = threadIdx.x & 63;
    const int wid  = threadIdx.x >> 6;
    const int d0   = blockIdx.x * CD;
    const int h    = blockIdx.y * 8 + 2 * wid; // wave's output rows h, h+1
    const int b    = blockIdx.z;

    // per-lane bases: 3 w-elements per lane, all 64 lanes active
    const float* sb0 = pred + (size_t)b * ND * PLI + 3 * lane;
    const float* sb1 = targ + (size_t)b * ND * PLI + 3 * lane;

    // 4 input rows h-1..h+2 (clamped) + wave-uniform edge masks
    const int ro0 = (h - 1 < 0 ? 0 : h - 1) * NW;
    const int ro1 = h * NW;
    const int ro2 = (h + 1) * NW;                      // always valid
    const int ro3 = (h + 2 > NH - 1 ? NH - 1 : h + 2) * NW;
    const float m0 = (h - 1 >= 0) ? 1.f : 0.f;
    const float m3 = (h + 2 < NH) ? 1.f : 0.f;

    // rolling UNSCALED conv state: q[tensor][slot][kind][row][w] = 108 floats
    float q[2][3][3][2][3];
    float acc = 0.f;

// write one output row's (ss,ts,st) from named u/v + halos (literal indices)
#define QROW(T, SP, R, U0, U1, U2, UM, UP, V0, V1, V2, VM, VP) do {           \
    q[T][SP][0][R][0] = fmaf(2.f, U0, UM + U1);                               \
    q[T][SP][0][R][1] = fmaf(2.f, U1, U0 + U2);                               \
    q[T][SP][0][R][2] = fmaf(2.f, U2, U1 + UP);                               \
    q[T][SP][1][R][0] = fmaf(2.f, V0, VM + V1);                               \
    q[T][SP][1][R][1] = fmaf(2.f, V1, V0 + V2);                               \
    q[T][SP][1][R][2] = fmaf(2.f, V2, V1 + VP);                               \
    q[T][SP][2][R][0] = U1 - UM;                                              \
    q[T][SP][2][R][1] = U2 - U0;                                              \
    q[T][SP][2][R][2] = UP - U1;                                              \
} while (0)

// one tensor, one plane, into slot SP. PM = plane mask (1.f when in range).
// 12 loads, h-conv for 2 output rows in registers, w-halo via 8 shuffles.
#define TPASS(T, SP, OFS, PM) do {                                            \
    const float* s_ = (T) ? sb1 : sb0;                                        \
    float a0_ = s_[(OFS) + ro0], a1_ = s_[(OFS) + ro0 + 1], a2_ = s_[(OFS) + ro0 + 2]; \
    float b0_ = s_[(OFS) + ro1], b1_ = s_[(OFS) + ro1 + 1], b2_ = s_[(OFS) + ro1 + 2]; \
    float c0_ = s_[(OFS) + ro2], c1_ = s_[(OFS) + ro2 + 1], c2_ = s_[(OFS) + ro2 + 2]; \
    float d0_ = s_[(OFS) + ro3], d1_ = s_[(OFS) + ro3 + 1], d2_ = s_[(OFS) + ro3 + 2]; \
    a0_ *= m0; a1_ *= m0; a2_ *= m0;                                          \
    d0_ *= m3; d1_ *= m3; d2_ *= m3;                                          \
    float uA0_ = fmaf(2.f, b0_, a0_ + c0_) * (PM);                            \
    float uA1_ = fmaf(2.f, b1_, a1_ + c1_) * (PM);                            \
    float uA2_ = fmaf(2.f, b2_, a2_ + c2_) * (PM);                            \
    float uB0_ = fmaf(2.f, c0_, b0_ + d0_) * (PM);                            \
    float uB1_ = fmaf(2.f, c1_, b1_ + d1_) * (PM);                            \
    float uB2_ = fmaf(2.f, c2_, b2_ + d2_) * (PM);                            \
    float vA0_ = (c0_ - a0_) * (PM), vA1_ = (c1_ - a1_) * (PM), vA2_ = (c2_ - a2_) * (PM); \
    float vB0_ = (d0_ - b0_) * (PM), vB1_ = (d1_ - b1_) * (PM), vB2_ = (d2_ - b2_) * (PM); \
    float uAm_ = __shfl_up(uA2_, 1, 64), uAp_ = __shfl_down(uA0_, 1, 64);     \
    float uBm_ = __shfl_up(uB2_, 1, 64), uBp_ = __shfl_down(uB0_, 1, 64);     \
    float vAm_ = __shfl_up(vA2_, 1, 64), vAp_ = __shfl_down(vA0_, 1, 64);     \
    float vBm_ = __shfl_up(vB2_, 1, 64), vBp_ = __shfl_down(vB0_, 1, 64);     \
    if (lane == 0)  { uAm_ = 0.f; uBm_ = 0.f; vAm_ = 0.f; vBm_ = 0.f; }       \
    if (lane == 63) { uAp_ = 0.f; uBp_ = 0.f; vAp_ = 0.f; vBp_ = 0.f; }       \
    QROW(T, SP, 0, uA0_, uA1_, uA2_, uAm_, uAp_, vA0_, vA1_, vA2_, vAm_, vAp_); \
    QROW(T, SP, 1, uB0_, uB1_, uB2_, uBm_, uBp_, vB0_, vB1_, vB2_, vBm_, vBp_); \
} while (0)

// both tensors, plane P guaranteed in range
#define TPP(SP, P) do {                                                       \
    const int o_ = (P) * PLI;                                                 \
    TPASS(0, SP, o_, 1.f); TPASS(1, SP, o_, 1.f);                             \
} while (0)

// both tensors, plane P may be out of range (blocks at d-edges)
#define TPM(SP, P) do {                                                       \
    const int pc_ = (P) < 0 ? 0 : ((P) > ND - 1 ? ND - 1 : (P));              \
    const float pm_ = ((P) >= 0 && (P) < ND) ? 1.f : 0.f;                     \
    const int o_ = pc_ * PLI;                                                 \
    TPASS(0, SP, o_, pm_); TPASS(1, SP, o_, pm_);                             \
} while (0)

// unscaled magnitude: conv scales exactly 16x; eps_u = 256e-8; v_sqrt 1 inst
#define EDGE1(T, R, J, SM, SC, SP, E) do {                                    \
    const float gx_ = fmaf(2.f, q[T][SC][2][R][J], q[T][SM][2][R][J] + q[T][SP][2][R][J]); \
    const float gy_ = fmaf(2.f, q[T][SC][1][R][J], q[T][SM][1][R][J] + q[T][SP][1][R][J]); \
    const float gz_ = q[T][SP][0][R][J] - q[T][SM][0][R][J];                  \
    const float d_ = fmaf(gz_, gz_, fmaf(gy_, gy_, fmaf(gx_, gx_, 2.56e-6f)));\
    asm("v_sqrt_f32 %0, %1" : "=v"(E) : "v"(d_));                             \
} while (0)

#define EMIT1(R, J, SM, SC, SP) do {                                          \
    float e0_, e1_;                                                           \
    EDGE1(0, R, J, SM, SC, SP, e0_);                                          \
    EDGE1(1, R, J, SM, SC, SP, e1_);                                          \
    acc += fabsf(e0_ - e1_);                                                  \
} while (0)

#define EMIT(SM, SC, SP) do {                                                 \
    EMIT1(0, 0, SM, SC, SP); EMIT1(0, 1, SM, SC, SP); EMIT1(0, 2, SM, SC, SP);\
    EMIT1(1, 0, SM, SC, SP); EMIT1(1, 1, SM, SC, SP); EMIT1(1, 2, SM, SC, SP);\
} while (0)

    // 18 phases k=0..17: plane d0-1+k -> slot k%3; EMIT from k>=2. No barriers.
    TPM(0, d0 - 1);                           // k=0 (OOB only for first block)
    TPP(1, d0);                               // k=1
    for (int gg = 0; gg < 5; ++gg) {          // k=2..16
        const int p = d0 + 1 + 3 * gg;
        TPP(2, p);     EMIT(0, 1, 2);
        TPP(0, p + 1); EMIT(1, 2, 0);
        TPP(1, p + 2); EMIT(2, 0, 1);
    }
    TPM(2, d0 + 16); EMIT(0, 1, 2);           // k=17 (OOB only for last block)

#undef QROW
#undef TPASS
#undef TPP
#undef TPM
#undef EDGE1
#undef EMIT1
#undef EMIT

    // wave reduce -> block reduce -> one atomic per block
    #pragma unroll
    for (int off = 32; off > 0; off >>= 1)
        acc += __shfl_down(acc, off, 64);
    __shared__ float wsum[4];
    if (lane == 0) wsum[wid] = acc;
    __syncthreads();
    if (threadIdx.x == 0) {
        // fold the exact 1/16 kernel scale and the mean into one constant
        const float invN = 1.f / (16.f * (float)((long long)NB * ND * NH * NW));
        atomicAdd(out, (wsum[0] + wsum[1] + wsum[2] + wsum[3]) * invN);
    }
}

} // namespace

extern "C" void kernel_launch(void* const* d_in, const int* in_sizes, int n_in,
                              void* d_out, int out_size, void* d_ws, size_t ws_size,
                              hipStream_t stream) {
    const float* pred = (const float*)d_in[0];
    const float* targ = (const float*)d_in[1];
    float* out = (float*)d_out;
    (void)in_sizes; (void)n_in; (void)out_size; (void)d_ws; (void)ws_size;

    hipMemsetAsync(out, 0, sizeof(float), stream);

    dim3 grid(ND / CD, NH / 8, NB);   // (8, 24, 4) = 768 blocks, 12 waves/CU
    dim3 block(256);
    edge_loss3d<<<grid, block, 0, stream>>>(pred, targ, out);
}